// Round 9
// baseline (198.064 us; speedup 1.0000x reference)
//
#include <hip/hip_runtime.h>

#define EPS 1e-5f

typedef float f32x4 __attribute__((ext_vector_type(4)));
typedef short s16x8 __attribute__((ext_vector_type(8)));

union FragU { uint4 u; s16x8 s; };

__device__ __forceinline__ float ht(float x){ return fminf(fmaxf(x,-1.f),1.f); }
__device__ __forceinline__ float sgn(float v){ return (v>0.f)?1.f:((v<0.f)?-1.f:0.f); }
__device__ __forceinline__ unsigned short f2bf(float f){
    unsigned int u = __builtin_bit_cast(unsigned int, f);
    u += 0x7FFFu + ((u>>16)&1u);                 // RNE to bf16
    return (unsigned short)(u>>16);
}

// =============== prep (6 blocks): A-fragments + BN params ===============
__global__ __launch_bounds__(512) void prep(
    const float* __restrict__ w1, const float* __restrict__ w2, const float* __restrict__ w3,
    const float* g1,const float* b1,const float* m1,const float* v1,
    const float* g2,const float* b2,const float* m2,const float* v2,
    const float* g3,const float* b3,const float* m3,const float* v3,
    unsigned short* __restrict__ a1, unsigned short* __restrict__ a2,
    unsigned short* __restrict__ a3, float* __restrict__ bn){
  const int t = threadIdx.x, bid = blockIdx.x;
  if(bid == 0){
    if(t < 64){                                  // conv1: K=32 (k<17 real)
      int q = t>>4, m = t&15;
      #pragma unroll
      for(int j=0;j<8;++j){ int k = 8*q+j;
        a1[t*8+j] = f2bf((k<17)? w1[m*17+k] : 0.f); }
    }
    if(t<16){ float s = g1[t]*rsqrtf(v1[t]+EPS); bn[t]    = s; bn[16+t]  = b1[t]-m1[t]*s; }
    if(t<32){ float s = g2[t]*rsqrtf(v2[t]+EPS); bn[32+t] = s; bn[64+t]  = b2[t]-m2[t]*s; }
    if(t<64){ float s = g3[t]*rsqrtf(v3[t]+EPS); bn[96+t] = s; bn[160+t] = b3[t]-m3[t]*s; }
  } else if(bid <= 2){                           // conv2: [h2][c5][q4][m16], k-major K=160
    int e = (bid-1)*512 + t;
    if(e < 640){
      int m = e&15, q = (e>>4)&3, hc = e>>6, c = hc%5, h = hc/5;
      int oc = m + 16*h, k = 2*c + (q>>1);
      #pragma unroll
      for(int j=0;j<8;++j){ int ic = 8*(q&1)+j;
        a2[e*8+j] = f2bf((k<9)? sgn(w2[(oc*16+ic)*9+k]) : 0.f); }
    }
  } else {                                       // conv3: [g4][c5][q4][m16], K=160
    int e = (bid-3)*512 + t;
    if(e < 1280){
      int m = e&15, q = (e>>4)&3, gc = e>>6, c = gc%5, g = gc/5;
      int oc = m + 16*g;
      #pragma unroll
      for(int j=0;j<8;++j){ int ic = 8*q+j;
        a3[e*8+j] = f2bf(sgn(w3[(oc*32+ic)*5+c])); }
    }
  }
}

// =============== fused: x -> conv1 -> conv2 -> conv3 -> partial feature sums ===========
// Block owns 16 final pooled positions [Q0,Q0+16), Q0 = 16*(blockIdx&15). Grid = 256*16.
// ~22 KB LDS, <=64 VGPR -> 4 blocks/CU (wave-capped). No inter-block sync (kfc follows).
__global__ __launch_bounds__(512, 8) void kfused(const float* __restrict__ x,
    const unsigned short* __restrict__ a1, const unsigned short* __restrict__ a2,
    const unsigned short* __restrict__ a3, const float* __restrict__ bn,
    float* __restrict__ partial){
  __shared__ __align__(16) unsigned short xs[1160];      // x[x0 .. x0+1152) bf16
  __shared__ __align__(16) unsigned short s1[296*24];    // [p1 local][16 oc]; 280 used
  __shared__ __align__(16) unsigned short s2[68*40];     // [p2 local][32 oc]
  __shared__ float fws[8*16];
  const int b  = blockIdx.x >> 4;
  const int t  = blockIdx.x & 15;
  const int Q0 = 16*t;
  const int tid = threadIdx.x;
  const int m = tid & 15, q = (tid & 63) >> 4, w = tid >> 6;

  // ---- stage x -> xs (g0 always 4-aligned -> full-in/full-out float4 guard) ----
  const int x0 = 64*Q0 - 56;
  const float* xrow = &x[b*16384];
  for(int i = tid; i < 288; i += 512){
    int g0 = x0 + 4*i;
    float4 v = make_float4(0.f,0.f,0.f,0.f);
    if(g0 >= 0 && g0 <= 16380) v = *(const float4*)&xrow[g0];
    uint2 pk;
    pk.x = (unsigned)f2bf(v.x) | ((unsigned)f2bf(v.y)<<16);
    pk.y = (unsigned)f2bf(v.z) | ((unsigned)f2bf(v.w)<<16);
    *(uint2*)&xs[4*i] = pk;
  }
  FragU af1; af1.u = *(const uint4*)&a1[(q*16+m)*8];
  const float4 sc1 = *(const float4*)&bn[4*q];
  const float4 sh1 = *(const float4*)&bn[16+4*q];
  __syncthreads();

  // ---- stage 1: conv1 on 560 pre-pool columns (35 tiles) -> s1[280][16] ----
  const unsigned* X32 = (const unsigned*)xs;
  for(int it = 0; it < 5; ++it){
    int tile = it*8 + w;                         // wave-uniform guard
    if(tile < 35){
      int nl = tile*16 + m;
      int d = nl + 4*q;
      FragU bf;
      bf.u.x = X32[d]; bf.u.y = X32[d+1]; bf.u.z = X32[d+2]; bf.u.w = X32[d+3];
      f32x4 acc = {0.f,0.f,0.f,0.f};
      acc = __builtin_amdgcn_mfma_f32_16x16x32_bf16(af1.s, bf.s, acc, 0,0,0);
      float r0 = ht(acc[0]*sc1.x + sh1.x);
      float r1 = ht(acc[1]*sc1.y + sh1.y);
      float r2 = ht(acc[2]*sc1.z + sh1.z);
      float r3 = ht(acc[3]*sc1.w + sh1.w);
      float p0 = fmaxf(r0, __shfl_xor(r0,1,64));
      float p1 = fmaxf(r1, __shfl_xor(r1,1,64));
      float p2 = fmaxf(r2, __shfl_xor(r2,1,64));
      float p3 = fmaxf(r3, __shfl_xor(r3,1,64));
      if((m&1)==0){
        int ppl = nl >> 1;
        bool ok = (unsigned)(16*Q0 - 12 + ppl) < 4096u;  // reference zero-pad
        uint2 pk;
        pk.x = ok ? ((unsigned)f2bf(p0) | ((unsigned)f2bf(p1)<<16)) : 0u;
        pk.y = ok ? ((unsigned)f2bf(p2) | ((unsigned)f2bf(p3)<<16)) : 0u;
        *(uint2*)&s1[ppl*24 + 4*q] = pk;
      }
    }
  }
  __syncthreads();

  // ---- stage 2: conv2 on 136 pre-pool columns (9 tiles) -> s2[68][32] ----
  FragU af2[2][5];
  #pragma unroll
  for(int h=0;h<2;++h)
    #pragma unroll
    for(int c=0;c<5;++c)
      af2[h][c].u = *(const uint4*)&a2[(((h*5+c)*4+q)*16+m)*8];
  float4 sc2[2], sh2[2];
  #pragma unroll
  for(int h=0;h<2;++h){
    sc2[h] = *(const float4*)&bn[32 + 16*h + 4*q];
    sh2[h] = *(const float4*)&bn[64 + 16*h + 4*q];
  }
  for(int it = 0; it < 2; ++it){
    int tile = it*8 + w;                         // wave-uniform guard
    if(tile < 9){
      int nl = tile*16 + m;
      f32x4 acc[2] = {{0.f,0.f,0.f,0.f},{0.f,0.f,0.f,0.f}};
      #pragma unroll
      for(int c=0;c<5;++c){
        int row = 2*nl + 2*c + (q>>1);           // row <= 295 (s1 has margin)
        FragU bf; bf.u = *(const uint4*)&s1[row*24 + 8*(q&1)];
        acc[0] = __builtin_amdgcn_mfma_f32_16x16x32_bf16(af2[0][c].s, bf.s, acc[0],0,0,0);
        acc[1] = __builtin_amdgcn_mfma_f32_16x16x32_bf16(af2[1][c].s, bf.s, acc[1],0,0,0);
      }
      #pragma unroll
      for(int h=0;h<2;++h){
        float r0 = ht(acc[h][0]*sc2[h].x + sh2[h].x);
        float r1 = ht(acc[h][1]*sc2[h].y + sh2[h].y);
        float r2 = ht(acc[h][2]*sc2[h].z + sh2[h].z);
        float r3 = ht(acc[h][3]*sc2[h].w + sh2[h].w);
        float p0 = fmaxf(r0, __shfl_xor(r0,1,64));
        float p1 = fmaxf(r1, __shfl_xor(r1,1,64));
        float p2 = fmaxf(r2, __shfl_xor(r2,1,64));
        float p3 = fmaxf(r3, __shfl_xor(r3,1,64));
        if((m&1)==0 && nl < 136){
          int ppl = nl >> 1;
          bool ok = (unsigned)(4*Q0 - 2 + ppl) < 1024u;  // reference zero-pad
          uint2 pk;
          pk.x = ok ? ((unsigned)f2bf(p0) | ((unsigned)f2bf(p1)<<16)) : 0u;
          pk.y = ok ? ((unsigned)f2bf(p2) | ((unsigned)f2bf(p3)<<16)) : 0u;
          *(uint2*)&s2[ppl*40 + 16*h + 4*q] = pk;
        }
      }
    }
  }
  __syncthreads();

  // ---- stage 3: conv3 on 32 pre-pool columns; wave = (tile w&1, oc-group w>>1) ----
  const int og = w >> 1, tw = w & 1;             // og in [0,4): oc group of 16
  FragU af3[5];
  #pragma unroll
  for(int c=0;c<5;++c)
    af3[c].u = *(const uint4*)&a3[(((og*5+c)*4+q)*16+m)*8];
  const float4 sc3 = *(const float4*)&bn[96  + 16*og + 4*q];
  const float4 sh3 = *(const float4*)&bn[160 + 16*og + 4*q];
  {
    int nl = tw*16 + m;
    f32x4 acc = {0.f,0.f,0.f,0.f};
    #pragma unroll
    for(int c=0;c<5;++c){
      int row = 2*nl + c;                        // row <= 66 < 68
      FragU bf; bf.u = *(const uint4*)&s2[row*40 + 8*q];
      acc = __builtin_amdgcn_mfma_f32_16x16x32_bf16(af3[c].s, bf.s, acc, 0,0,0);
    }
    float r0 = ht(acc[0]*sc3.x + sh3.x);
    float r1 = ht(acc[1]*sc3.y + sh3.y);
    float r2 = ht(acc[2]*sc3.z + sh3.z);
    float r3 = ht(acc[3]*sc3.w + sh3.w);
    float p0 = fmaxf(r0, __shfl_xor(r0,1,64));
    float p1 = fmaxf(r1, __shfl_xor(r1,1,64));
    float p2 = fmaxf(r2, __shfl_xor(r2,1,64));
    float p3 = fmaxf(r3, __shfl_xor(r3,1,64));
    // xor-2/4/8 tree stays in one parity class: each pooled value summed ONCE
    p0 += __shfl_xor(p0,2,64); p0 += __shfl_xor(p0,4,64); p0 += __shfl_xor(p0,8,64);
    p1 += __shfl_xor(p1,2,64); p1 += __shfl_xor(p1,4,64); p1 += __shfl_xor(p1,8,64);
    p2 += __shfl_xor(p2,2,64); p2 += __shfl_xor(p2,4,64); p2 += __shfl_xor(p2,8,64);
    p3 += __shfl_xor(p3,2,64); p3 += __shfl_xor(p3,4,64); p3 += __shfl_xor(p3,8,64);
    if(m == 0)
      *(float4*)&fws[w*16 + 4*q] = make_float4(p0,p1,p2,p3);
  }
  __syncthreads();
  if(tid < 64){
    int og2 = tid >> 4, ocl = tid & 15;          // oc = 16*og2 + ocl
    float sum = fws[(2*og2)*16 + ocl] + fws[(2*og2+1)*16 + ocl];
    partial[(b*16 + t)*64 + tid] = sum;
  }
}

// =============== kfc: reduce partials + fc1 + ht + fc2 -> out[B,2] ======================
__global__ __launch_bounds__(64) void kfc(const float* __restrict__ partial,
    const float* __restrict__ rms, const float* __restrict__ fc1w,
    const float* __restrict__ fc1b, const float* __restrict__ fc2w,
    const float* __restrict__ fc2b, float* __restrict__ out){
  __shared__ float feat[64];
  __shared__ float hbuf[32];
  const int b = blockIdx.x, tid = threadIdx.x;
  float s = 0.f;
  #pragma unroll
  for(int t = 0; t < 16; ++t) s += partial[(b*16 + t)*64 + tid];
  feat[tid] = s * (1.f/256.f);
  __syncthreads();
  if(tid < 32){
    float acc = fc1b[tid];
    const float* wv = &fc1w[tid*65];
    #pragma unroll
    for(int c = 0; c < 64; ++c) acc += wv[c]*feat[c];
    acc += wv[64]*rms[b];
    hbuf[tid] = ht(acc);
  }
  __syncthreads();
  if(tid < 2){
    float acc = fc2b[tid];
    const float* wv = &fc2w[tid*32];
    #pragma unroll
    for(int j = 0; j < 32; ++j) acc += wv[j]*hbuf[j];
    out[b*2 + tid] = acc;
  }
}

extern "C" void kernel_launch(void* const* d_in, const int* in_sizes, int n_in,
                              void* d_out, int out_size, void* d_ws, size_t ws_size,
                              hipStream_t stream){
  (void)in_sizes; (void)n_in; (void)out_size; (void)ws_size;
  const float* x    = (const float*)d_in[0];
  const float* rms  = (const float*)d_in[1];
  const float* w1   = (const float*)d_in[2];
  const float* g1   = (const float*)d_in[3];
  const float* b1   = (const float*)d_in[4];
  const float* m1   = (const float*)d_in[5];
  const float* v1   = (const float*)d_in[6];
  const float* w2   = (const float*)d_in[7];
  const float* g2   = (const float*)d_in[8];
  const float* b2   = (const float*)d_in[9];
  const float* m2   = (const float*)d_in[10];
  const float* v2   = (const float*)d_in[11];
  const float* w3   = (const float*)d_in[12];
  const float* g3   = (const float*)d_in[13];
  const float* b3   = (const float*)d_in[14];
  const float* m3   = (const float*)d_in[15];
  const float* v3   = (const float*)d_in[16];
  const float* fc1w = (const float*)d_in[17];
  const float* fc1b = (const float*)d_in[18];
  const float* fc2w = (const float*)d_in[19];
  const float* fc2b = (const float*)d_in[20];
  float* out  = (float*)d_out;

  // ws layout
  float*          partial = (float*)d_ws;                      // 256*16*64 f32 (1 MB)
  unsigned short* a1  = (unsigned short*)(partial + 262144);   //   512 bf16
  unsigned short* a2  = a1 + 512;                              //  5120 bf16
  unsigned short* a3  = a2 + 5120;                             // 10240 bf16
  float*          bnp = (float*)(a3 + 10240);                  //   224 f32 (16B aligned)

  prep<<<6,    512, 0, stream>>>(w1, w2, w3, g1,b1,m1,v1, g2,b2,m2,v2, g3,b3,m3,v3,
                                 a1, a2, a3, bnp);
  kfused<<<4096, 512, 0, stream>>>(x, a1, a2, a3, bnp, partial);
  kfc<<<256, 64, 0, stream>>>(partial, rms, fc1w, fc1b, fc2w, fc2b, out);
}

// Round 10
// 144.931 us; speedup vs baseline: 1.3666x; 1.3666x over previous
//
#include <hip/hip_runtime.h>

#define EPS 1e-5f

typedef float f32x4 __attribute__((ext_vector_type(4)));
typedef short s16x8 __attribute__((ext_vector_type(8)));

union FragU { uint4 u; s16x8 s; };

__device__ __forceinline__ float ht(float x){ return fminf(fmaxf(x,-1.f),1.f); }
__device__ __forceinline__ float sgn(float v){ return (v>0.f)?1.f:((v<0.f)?-1.f:0.f); }
__device__ __forceinline__ unsigned short f2bf(float f){
    unsigned int u = __builtin_bit_cast(unsigned int, f);
    u += 0x7FFFu + ((u>>16)&1u);                 // RNE to bf16
    return (unsigned short)(u>>16);
}

// =============== prep (6 blocks): A-fragments + BN params ===============
__global__ __launch_bounds__(512) void prep(
    const float* __restrict__ w1, const float* __restrict__ w2, const float* __restrict__ w3,
    const float* g1,const float* b1,const float* m1,const float* v1,
    const float* g2,const float* b2,const float* m2,const float* v2,
    const float* g3,const float* b3,const float* m3,const float* v3,
    unsigned short* __restrict__ a1, unsigned short* __restrict__ a2,
    unsigned short* __restrict__ a3, float* __restrict__ bn){
  const int t = threadIdx.x, bid = blockIdx.x;
  if(bid == 0){
    if(t < 64){                                  // conv1: K=32 (k<17 real)
      int q = t>>4, m = t&15;
      #pragma unroll
      for(int j=0;j<8;++j){ int k = 8*q+j;
        a1[t*8+j] = f2bf((k<17)? w1[m*17+k] : 0.f); }
    }
    if(t<16){ float s = g1[t]*rsqrtf(v1[t]+EPS); bn[t]    = s; bn[16+t]  = b1[t]-m1[t]*s; }
    if(t<32){ float s = g2[t]*rsqrtf(v2[t]+EPS); bn[32+t] = s; bn[64+t]  = b2[t]-m2[t]*s; }
    if(t<64){ float s = g3[t]*rsqrtf(v3[t]+EPS); bn[96+t] = s; bn[160+t] = b3[t]-m3[t]*s; }
  } else if(bid <= 2){                           // conv2: [h2][c5][q4][m16], k-major K=160
    int e = (bid-1)*512 + t;
    if(e < 640){
      int m = e&15, q = (e>>4)&3, hc = e>>6, c = hc%5, h = hc/5;
      int oc = m + 16*h, k = 2*c + (q>>1);
      #pragma unroll
      for(int j=0;j<8;++j){ int ic = 8*(q&1)+j;
        a2[e*8+j] = f2bf((k<9)? sgn(w2[(oc*16+ic)*9+k]) : 0.f); }
    }
  } else {                                       // conv3: [g4][c5][q4][m16], K=160
    int e = (bid-3)*512 + t;
    if(e < 1280){
      int m = e&15, q = (e>>4)&3, gc = e>>6, c = gc%5, g = gc/5;
      int oc = m + 16*g;
      #pragma unroll
      for(int j=0;j<8;++j){ int ic = 8*q+j;
        a3[e*8+j] = f2bf(sgn(w3[(oc*32+ic)*5+c])); }
    }
  }
}

// =============== fused: x -> conv1 -> conv2 -> conv3 -> partial feature sums ===========
// Block owns 16 final pooled positions [Q0,Q0+16), Q0 = 16*(blockIdx&15). Grid = 256*16.
// ~22 KB LDS; launch_bounds(512,4): VGPR cap 128 -> NO SPILL (R9's (512,8) cap=64 spilled:
// 375 MB/dispatch scratch traffic). Occupancy 4 blocks/CU (wave-capped) either way.
__global__ __launch_bounds__(512, 4) void kfused(const float* __restrict__ x,
    const unsigned short* __restrict__ a1, const unsigned short* __restrict__ a2,
    const unsigned short* __restrict__ a3, const float* __restrict__ bn,
    float* __restrict__ partial){
  __shared__ __align__(16) unsigned short xs[1160];      // x[x0 .. x0+1152) bf16
  __shared__ __align__(16) unsigned short s1[296*24];    // [p1 local][16 oc]; 280 used
  __shared__ __align__(16) unsigned short s2[68*40];     // [p2 local][32 oc]
  __shared__ float fws[8*16];
  const int b  = blockIdx.x >> 4;
  const int t  = blockIdx.x & 15;
  const int Q0 = 16*t;
  const int tid = threadIdx.x;
  const int m = tid & 15, q = (tid & 63) >> 4, w = tid >> 6;

  // ---- stage x -> xs (g0 always 4-aligned -> full-in/full-out float4 guard) ----
  const int x0 = 64*Q0 - 56;
  const float* xrow = &x[b*16384];
  for(int i = tid; i < 288; i += 512){
    int g0 = x0 + 4*i;
    float4 v = make_float4(0.f,0.f,0.f,0.f);
    if(g0 >= 0 && g0 <= 16380) v = *(const float4*)&xrow[g0];
    uint2 pk;
    pk.x = (unsigned)f2bf(v.x) | ((unsigned)f2bf(v.y)<<16);
    pk.y = (unsigned)f2bf(v.z) | ((unsigned)f2bf(v.w)<<16);
    *(uint2*)&xs[4*i] = pk;
  }
  FragU af1; af1.u = *(const uint4*)&a1[(q*16+m)*8];
  const float4 sc1 = *(const float4*)&bn[4*q];
  const float4 sh1 = *(const float4*)&bn[16+4*q];
  __syncthreads();

  // ---- stage 1: conv1 on 560 pre-pool columns (35 tiles) -> s1[280][16] ----
  const unsigned* X32 = (const unsigned*)xs;
  for(int it = 0; it < 5; ++it){
    int tile = it*8 + w;                         // wave-uniform guard
    if(tile < 35){
      int nl = tile*16 + m;
      int d = nl + 4*q;
      FragU bf;
      bf.u.x = X32[d]; bf.u.y = X32[d+1]; bf.u.z = X32[d+2]; bf.u.w = X32[d+3];
      f32x4 acc = {0.f,0.f,0.f,0.f};
      acc = __builtin_amdgcn_mfma_f32_16x16x32_bf16(af1.s, bf.s, acc, 0,0,0);
      float r0 = ht(acc[0]*sc1.x + sh1.x);
      float r1 = ht(acc[1]*sc1.y + sh1.y);
      float r2 = ht(acc[2]*sc1.z + sh1.z);
      float r3 = ht(acc[3]*sc1.w + sh1.w);
      float p0 = fmaxf(r0, __shfl_xor(r0,1,64));
      float p1 = fmaxf(r1, __shfl_xor(r1,1,64));
      float p2 = fmaxf(r2, __shfl_xor(r2,1,64));
      float p3 = fmaxf(r3, __shfl_xor(r3,1,64));
      if((m&1)==0){
        int ppl = nl >> 1;
        bool ok = (unsigned)(16*Q0 - 12 + ppl) < 4096u;  // reference zero-pad
        uint2 pk;
        pk.x = ok ? ((unsigned)f2bf(p0) | ((unsigned)f2bf(p1)<<16)) : 0u;
        pk.y = ok ? ((unsigned)f2bf(p2) | ((unsigned)f2bf(p3)<<16)) : 0u;
        *(uint2*)&s1[ppl*24 + 4*q] = pk;
      }
    }
  }
  __syncthreads();

  // ---- stage 2: conv2 on 136 pre-pool columns (9 tiles) -> s2[68][32] ----
  FragU af2[2][5];
  #pragma unroll
  for(int h=0;h<2;++h)
    #pragma unroll
    for(int c=0;c<5;++c)
      af2[h][c].u = *(const uint4*)&a2[(((h*5+c)*4+q)*16+m)*8];
  float4 sc2[2], sh2[2];
  #pragma unroll
  for(int h=0;h<2;++h){
    sc2[h] = *(const float4*)&bn[32 + 16*h + 4*q];
    sh2[h] = *(const float4*)&bn[64 + 16*h + 4*q];
  }
  for(int it = 0; it < 2; ++it){
    int tile = it*8 + w;                         // wave-uniform guard
    if(tile < 9){
      int nl = tile*16 + m;
      f32x4 acc[2] = {{0.f,0.f,0.f,0.f},{0.f,0.f,0.f,0.f}};
      #pragma unroll
      for(int c=0;c<5;++c){
        int row = 2*nl + 2*c + (q>>1);           // row <= 295 (s1 has margin)
        FragU bf; bf.u = *(const uint4*)&s1[row*24 + 8*(q&1)];
        acc[0] = __builtin_amdgcn_mfma_f32_16x16x32_bf16(af2[0][c].s, bf.s, acc[0],0,0,0);
        acc[1] = __builtin_amdgcn_mfma_f32_16x16x32_bf16(af2[1][c].s, bf.s, acc[1],0,0,0);
      }
      #pragma unroll
      for(int h=0;h<2;++h){
        float r0 = ht(acc[h][0]*sc2[h].x + sh2[h].x);
        float r1 = ht(acc[h][1]*sc2[h].y + sh2[h].y);
        float r2 = ht(acc[h][2]*sc2[h].z + sh2[h].z);
        float r3 = ht(acc[h][3]*sc2[h].w + sh2[h].w);
        float p0 = fmaxf(r0, __shfl_xor(r0,1,64));
        float p1 = fmaxf(r1, __shfl_xor(r1,1,64));
        float p2 = fmaxf(r2, __shfl_xor(r2,1,64));
        float p3 = fmaxf(r3, __shfl_xor(r3,1,64));
        if((m&1)==0 && nl < 136){
          int ppl = nl >> 1;
          bool ok = (unsigned)(4*Q0 - 2 + ppl) < 1024u;  // reference zero-pad
          uint2 pk;
          pk.x = ok ? ((unsigned)f2bf(p0) | ((unsigned)f2bf(p1)<<16)) : 0u;
          pk.y = ok ? ((unsigned)f2bf(p2) | ((unsigned)f2bf(p3)<<16)) : 0u;
          *(uint2*)&s2[ppl*40 + 16*h + 4*q] = pk;
        }
      }
    }
  }
  __syncthreads();

  // ---- stage 3: conv3 on 32 pre-pool columns; wave = (tile w&1, oc-group w>>1) ----
  const int og = w >> 1, tw = w & 1;             // og in [0,4): oc group of 16
  FragU af3[5];
  #pragma unroll
  for(int c=0;c<5;++c)
    af3[c].u = *(const uint4*)&a3[(((og*5+c)*4+q)*16+m)*8];
  const float4 sc3 = *(const float4*)&bn[96  + 16*og + 4*q];
  const float4 sh3 = *(const float4*)&bn[160 + 16*og + 4*q];
  {
    int nl = tw*16 + m;
    f32x4 acc = {0.f,0.f,0.f,0.f};
    #pragma unroll
    for(int c=0;c<5;++c){
      int row = 2*nl + c;                        // row <= 66 < 68
      FragU bf; bf.u = *(const uint4*)&s2[row*40 + 8*q];
      acc = __builtin_amdgcn_mfma_f32_16x16x32_bf16(af3[c].s, bf.s, acc, 0,0,0);
    }
    float r0 = ht(acc[0]*sc3.x + sh3.x);
    float r1 = ht(acc[1]*sc3.y + sh3.y);
    float r2 = ht(acc[2]*sc3.z + sh3.z);
    float r3 = ht(acc[3]*sc3.w + sh3.w);
    float p0 = fmaxf(r0, __shfl_xor(r0,1,64));
    float p1 = fmaxf(r1, __shfl_xor(r1,1,64));
    float p2 = fmaxf(r2, __shfl_xor(r2,1,64));
    float p3 = fmaxf(r3, __shfl_xor(r3,1,64));
    // xor-2/4/8 tree stays in one parity class: each pooled value summed ONCE
    p0 += __shfl_xor(p0,2,64); p0 += __shfl_xor(p0,4,64); p0 += __shfl_xor(p0,8,64);
    p1 += __shfl_xor(p1,2,64); p1 += __shfl_xor(p1,4,64); p1 += __shfl_xor(p1,8,64);
    p2 += __shfl_xor(p2,2,64); p2 += __shfl_xor(p2,4,64); p2 += __shfl_xor(p2,8,64);
    p3 += __shfl_xor(p3,2,64); p3 += __shfl_xor(p3,4,64); p3 += __shfl_xor(p3,8,64);
    if(m == 0)
      *(float4*)&fws[w*16 + 4*q] = make_float4(p0,p1,p2,p3);
  }
  __syncthreads();
  if(tid < 64){
    int og2 = tid >> 4, ocl = tid & 15;          // oc = 16*og2 + ocl
    float sum = fws[(2*og2)*16 + ocl] + fws[(2*og2+1)*16 + ocl];
    partial[(b*16 + t)*64 + tid] = sum;
  }
}

// =============== kfc: reduce partials + fc1 + ht + fc2 -> out[B,2] ======================
__global__ __launch_bounds__(64) void kfc(const float* __restrict__ partial,
    const float* __restrict__ rms, const float* __restrict__ fc1w,
    const float* __restrict__ fc1b, const float* __restrict__ fc2w,
    const float* __restrict__ fc2b, float* __restrict__ out){
  __shared__ float feat[64];
  __shared__ float hbuf[32];
  const int b = blockIdx.x, tid = threadIdx.x;
  float s = 0.f;
  #pragma unroll
  for(int t = 0; t < 16; ++t) s += partial[(b*16 + t)*64 + tid];
  feat[tid] = s * (1.f/256.f);
  __syncthreads();
  if(tid < 32){
    float acc = fc1b[tid];
    const float* wv = &fc1w[tid*65];
    #pragma unroll
    for(int c = 0; c < 64; ++c) acc += wv[c]*feat[c];
    acc += wv[64]*rms[b];
    hbuf[tid] = ht(acc);
  }
  __syncthreads();
  if(tid < 2){
    float acc = fc2b[tid];
    const float* wv = &fc2w[tid*32];
    #pragma unroll
    for(int j = 0; j < 32; ++j) acc += wv[j]*hbuf[j];
    out[b*2 + tid] = acc;
  }
}

extern "C" void kernel_launch(void* const* d_in, const int* in_sizes, int n_in,
                              void* d_out, int out_size, void* d_ws, size_t ws_size,
                              hipStream_t stream){
  (void)in_sizes; (void)n_in; (void)out_size; (void)ws_size;
  const float* x    = (const float*)d_in[0];
  const float* rms  = (const float*)d_in[1];
  const float* w1   = (const float*)d_in[2];
  const float* g1   = (const float*)d_in[3];
  const float* b1   = (const float*)d_in[4];
  const float* m1   = (const float*)d_in[5];
  const float* v1   = (const float*)d_in[6];
  const float* w2   = (const float*)d_in[7];
  const float* g2   = (const float*)d_in[8];
  const float* b2   = (const float*)d_in[9];
  const float* m2   = (const float*)d_in[10];
  const float* v2   = (const float*)d_in[11];
  const float* w3   = (const float*)d_in[12];
  const float* g3   = (const float*)d_in[13];
  const float* b3   = (const float*)d_in[14];
  const float* m3   = (const float*)d_in[15];
  const float* v3   = (const float*)d_in[16];
  const float* fc1w = (const float*)d_in[17];
  const float* fc1b = (const float*)d_in[18];
  const float* fc2w = (const float*)d_in[19];
  const float* fc2b = (const float*)d_in[20];
  float* out  = (float*)d_out;

  // ws layout
  float*          partial = (float*)d_ws;                      // 256*16*64 f32 (1 MB)
  unsigned short* a1  = (unsigned short*)(partial + 262144);   //   512 bf16
  unsigned short* a2  = a1 + 512;                              //  5120 bf16
  unsigned short* a3  = a2 + 5120;                             // 10240 bf16
  float*          bnp = (float*)(a3 + 10240);                  //   224 f32 (16B aligned)

  prep<<<6,    512, 0, stream>>>(w1, w2, w3, g1,b1,m1,v1, g2,b2,m2,v2, g3,b3,m3,v3,
                                 a1, a2, a3, bnp);
  kfused<<<4096, 512, 0, stream>>>(x, a1, a2, a3, bnp, partial);
  kfc<<<256, 64, 0, stream>>>(partial, rms, fc1w, fc1b, fc2w, fc2b, out);
}

// Round 11
// 134.643 us; speedup vs baseline: 1.4710x; 1.0764x over previous
//
#include <hip/hip_runtime.h>

#define EPS 1e-5f

typedef float f32x4 __attribute__((ext_vector_type(4)));
typedef short s16x8 __attribute__((ext_vector_type(8)));

union FragU { uint4 u; s16x8 s; };

__device__ __forceinline__ float ht(float x){ return fminf(fmaxf(x,-1.f),1.f); }
__device__ __forceinline__ float sgn(float v){ return (v>0.f)?1.f:((v<0.f)?-1.f:0.f); }
__device__ __forceinline__ unsigned short f2bf(float f){
    unsigned int u = __builtin_bit_cast(unsigned int, f);
    u += 0x7FFFu + ((u>>16)&1u);                 // RNE to bf16
    return (unsigned short)(u>>16);
}

// DPP cross-lane on the VALU pipe (removes ds_swizzle from the DS pipe).
// Semantics HW-verified in R8 (absmax identical to shfl version).
#define DPP_XOR1 0xB1   // quad_perm(1,0,3,2): swap adjacent lanes
#define DPP_ROR1 0x121  // row (16-lane) rotate by 1
#define DPP_ROR2 0x122
#define DPP_ROR4 0x124
#define DPP_ROR8 0x128
template<int C>
__device__ __forceinline__ float dppf(float x){
  return __builtin_bit_cast(float, __builtin_amdgcn_update_dpp(
      0, __builtin_bit_cast(int, x), C, 0xF, 0xF, true));
}
__device__ __forceinline__ float poolmax(float r){ return fmaxf(r, dppf<DPP_XOR1>(r)); }
__device__ __forceinline__ float rowsum16(float s){   // full sum across the 16-lane row
  s += dppf<DPP_ROR8>(s); s += dppf<DPP_ROR4>(s);
  s += dppf<DPP_ROR2>(s); s += dppf<DPP_ROR1>(s);
  return s;                                           // pairs duplicated -> caller x0.5
}

// =============== prep (6 blocks): A-fragments + BN params ===============
__global__ __launch_bounds__(512) void prep(
    const float* __restrict__ w1, const float* __restrict__ w2, const float* __restrict__ w3,
    const float* g1,const float* b1,const float* m1,const float* v1,
    const float* g2,const float* b2,const float* m2,const float* v2,
    const float* g3,const float* b3,const float* m3,const float* v3,
    unsigned short* __restrict__ a1, unsigned short* __restrict__ a2,
    unsigned short* __restrict__ a3, float* __restrict__ bn){
  const int t = threadIdx.x, bid = blockIdx.x;
  if(bid == 0){
    if(t < 64){                                  // conv1: K=32 (k<17 real)
      int q = t>>4, m = t&15;
      #pragma unroll
      for(int j=0;j<8;++j){ int k = 8*q+j;
        a1[t*8+j] = f2bf((k<17)? w1[m*17+k] : 0.f); }
    }
    if(t<16){ float s = g1[t]*rsqrtf(v1[t]+EPS); bn[t]    = s; bn[16+t]  = b1[t]-m1[t]*s; }
    if(t<32){ float s = g2[t]*rsqrtf(v2[t]+EPS); bn[32+t] = s; bn[64+t]  = b2[t]-m2[t]*s; }
    if(t<64){ float s = g3[t]*rsqrtf(v3[t]+EPS); bn[96+t] = s; bn[160+t] = b3[t]-m3[t]*s; }
  } else if(bid <= 2){                           // conv2: [h2][c5][q4][m16], k-major K=160
    int e = (bid-1)*512 + t;
    if(e < 640){
      int m = e&15, q = (e>>4)&3, hc = e>>6, c = hc%5, h = hc/5;
      int oc = m + 16*h, k = 2*c + (q>>1);
      #pragma unroll
      for(int j=0;j<8;++j){ int ic = 8*(q&1)+j;
        a2[e*8+j] = f2bf((k<9)? sgn(w2[(oc*16+ic)*9+k]) : 0.f); }
    }
  } else {                                       // conv3: [g4][c5][q4][m16], K=160
    int e = (bid-3)*512 + t;
    if(e < 1280){
      int m = e&15, q = (e>>4)&3, gc = e>>6, c = gc%5, g = gc/5;
      int oc = m + 16*g;
      #pragma unroll
      for(int j=0;j<8;++j){ int ic = 8*q+j;
        a3[e*8+j] = f2bf(sgn(w3[(oc*32+ic)*5+c])); }
    }
  }
}

// =============== fused: x -> conv1 -> conv2 -> conv3 -> partial feature sums ===========
// Block owns 32 final pooled positions [Q0,Q0+32), Q0 = 32*(blockIdx&7). Grid = 256*8.
// ~43 KB LDS -> 3 blocks/CU; launch_bounds(512,4): VGPR cap 128, no spill.
// All cross-lane via DPP (VALU pipe) -> DS pipe only does the staging reads/writes.
__global__ __launch_bounds__(512, 4) void kfused(const float* __restrict__ x,
    const unsigned short* __restrict__ a1, const unsigned short* __restrict__ a2,
    const unsigned short* __restrict__ a3, const float* __restrict__ bn,
    float* __restrict__ partial){
  __shared__ __align__(16) unsigned short xs[2176];      // x[x0 .. x0+2176) bf16
  __shared__ __align__(16) unsigned short s1[552*24];    // [p1 local][16 oc], pad 24
  __shared__ __align__(16) unsigned short s2[132*40];    // [p2 local][32 oc], pad 40
  __shared__ float fws[8*32];
  const int b  = blockIdx.x >> 3;
  const int t  = blockIdx.x & 7;
  const int Q0 = 32*t;
  const int tid = threadIdx.x;
  const int m = tid & 15, q = (tid & 63) >> 4, w = tid >> 6;

  // ---- stage x -> xs ----
  const int x0 = 64*Q0 - 56;
  const float* xrow = &x[b*16384];
  for(int i = tid; i < 544; i += 512){
    int g0 = x0 + 4*i;
    float4 v = make_float4(0.f,0.f,0.f,0.f);
    if(g0 >= 0 && g0 <= 16380) v = *(const float4*)&xrow[g0];
    uint2 pk;
    pk.x = (unsigned)f2bf(v.x) | ((unsigned)f2bf(v.y)<<16);
    pk.y = (unsigned)f2bf(v.z) | ((unsigned)f2bf(v.w)<<16);
    *(uint2*)&xs[4*i] = pk;
  }
  FragU af1; af1.u = *(const uint4*)&a1[(q*16+m)*8];
  const float4 sc1 = *(const float4*)&bn[4*q];
  const float4 sh1 = *(const float4*)&bn[16+4*q];
  __syncthreads();

  // ---- stage 1: conv1 on 1072 pre-pool columns (67 tiles) -> s1[536][16] ----
  const unsigned* X32 = (const unsigned*)xs;
  for(int it = 0; it < 9; ++it){
    int tile = it*8 + w;                         // wave-uniform guard
    if(tile < 67){
      int nl = tile*16 + m;
      int d = nl + 4*q;
      FragU bf;
      bf.u.x = X32[d]; bf.u.y = X32[d+1]; bf.u.z = X32[d+2]; bf.u.w = X32[d+3];
      f32x4 acc = {0.f,0.f,0.f,0.f};
      acc = __builtin_amdgcn_mfma_f32_16x16x32_bf16(af1.s, bf.s, acc, 0,0,0);
      float p0 = poolmax(ht(acc[0]*sc1.x + sh1.x));
      float p1 = poolmax(ht(acc[1]*sc1.y + sh1.y));
      float p2 = poolmax(ht(acc[2]*sc1.z + sh1.z));
      float p3 = poolmax(ht(acc[3]*sc1.w + sh1.w));
      if((m&1)==0){
        int ppl = nl >> 1;
        bool ok = (unsigned)(16*Q0 - 12 + ppl) < 4096u;  // reference zero-pad
        uint2 pk;
        pk.x = ok ? ((unsigned)f2bf(p0) | ((unsigned)f2bf(p1)<<16)) : 0u;
        pk.y = ok ? ((unsigned)f2bf(p2) | ((unsigned)f2bf(p3)<<16)) : 0u;
        *(uint2*)&s1[ppl*24 + 4*q] = pk;
      }
    }
  }
  __syncthreads();

  // ---- stage 2: conv2 on 264 pre-pool columns (17 tiles) -> s2[132][32] ----
  FragU af2[2][5];
  #pragma unroll
  for(int h=0;h<2;++h)
    #pragma unroll
    for(int c=0;c<5;++c)
      af2[h][c].u = *(const uint4*)&a2[(((h*5+c)*4+q)*16+m)*8];
  float4 sc2[2], sh2[2];
  #pragma unroll
  for(int h=0;h<2;++h){
    sc2[h] = *(const float4*)&bn[32 + 16*h + 4*q];
    sh2[h] = *(const float4*)&bn[64 + 16*h + 4*q];
  }
  for(int it = 0; it < 3; ++it){
    int tile = it*8 + w;                         // wave-uniform guard
    if(tile < 17){
      int nl = tile*16 + m;
      f32x4 acc[2] = {{0.f,0.f,0.f,0.f},{0.f,0.f,0.f,0.f}};
      #pragma unroll
      for(int c=0;c<5;++c){
        int row = 2*nl + 2*c + (q>>1);           // row <= 551 < 552
        FragU bf; bf.u = *(const uint4*)&s1[row*24 + 8*(q&1)];
        acc[0] = __builtin_amdgcn_mfma_f32_16x16x32_bf16(af2[0][c].s, bf.s, acc[0],0,0,0);
        acc[1] = __builtin_amdgcn_mfma_f32_16x16x32_bf16(af2[1][c].s, bf.s, acc[1],0,0,0);
      }
      #pragma unroll
      for(int h=0;h<2;++h){
        float p0 = poolmax(ht(acc[h][0]*sc2[h].x + sh2[h].x));
        float p1 = poolmax(ht(acc[h][1]*sc2[h].y + sh2[h].y));
        float p2 = poolmax(ht(acc[h][2]*sc2[h].z + sh2[h].z));
        float p3 = poolmax(ht(acc[h][3]*sc2[h].w + sh2[h].w));
        if((m&1)==0 && nl < 264){
          int ppl = nl >> 1;
          bool ok = (unsigned)(4*Q0 - 2 + ppl) < 1024u;  // reference zero-pad
          uint2 pk;
          pk.x = ok ? ((unsigned)f2bf(p0) | ((unsigned)f2bf(p1)<<16)) : 0u;
          pk.y = ok ? ((unsigned)f2bf(p2) | ((unsigned)f2bf(p3)<<16)) : 0u;
          *(uint2*)&s2[ppl*40 + 16*h + 4*q] = pk;
        }
      }
    }
  }
  __syncthreads();

  // ---- stage 3: conv3 on 64 pre-pool columns; wave = (tile w&3, oc-half w>>2) ----
  const int gw = w >> 2, tw = w & 3;
  FragU af3[2][5];
  #pragma unroll
  for(int gl=0;gl<2;++gl)
    #pragma unroll
    for(int c=0;c<5;++c)
      af3[gl][c].u = *(const uint4*)&a3[((((2*gw+gl)*5+c)*4+q)*16+m)*8];
  float4 sc3[2], sh3[2];
  #pragma unroll
  for(int gl=0;gl<2;++gl){
    sc3[gl] = *(const float4*)&bn[96  + 16*(2*gw+gl) + 4*q];
    sh3[gl] = *(const float4*)&bn[160 + 16*(2*gw+gl) + 4*q];
  }
  {
    int nl = tw*16 + m;
    f32x4 acc[2] = {{0.f,0.f,0.f,0.f},{0.f,0.f,0.f,0.f}};
    #pragma unroll
    for(int c=0;c<5;++c){
      int row = 2*nl + c;                        // row <= 130 < 132
      FragU bf; bf.u = *(const uint4*)&s2[row*40 + 8*q];
      acc[0] = __builtin_amdgcn_mfma_f32_16x16x32_bf16(af3[0][c].s, bf.s, acc[0],0,0,0);
      acc[1] = __builtin_amdgcn_mfma_f32_16x16x32_bf16(af3[1][c].s, bf.s, acc[1],0,0,0);
    }
    #pragma unroll
    for(int gl=0;gl<2;++gl){
      float p0 = poolmax(ht(acc[gl][0]*sc3[gl].x + sh3[gl].x));
      float p1 = poolmax(ht(acc[gl][1]*sc3[gl].y + sh3[gl].y));
      float p2 = poolmax(ht(acc[gl][2]*sc3[gl].z + sh3[gl].z));
      float p3 = poolmax(ht(acc[gl][3]*sc3[gl].w + sh3[gl].w));
      // 16-lane rotate-sum counts each pooled value TWICE (pairs duplicated) -> x0.5
      float s0 = rowsum16(p0)*0.5f, s1v = rowsum16(p1)*0.5f;
      float s2v = rowsum16(p2)*0.5f, s3 = rowsum16(p3)*0.5f;
      if(m == 0)
        *(float4*)&fws[w*32 + 16*gl + 4*q] = make_float4(s0,s1v,s2v,s3);
    }
  }
  __syncthreads();
  if(tid < 64){
    int ocl = tid & 31;
    int wb  = (tid >> 5) * 4;                    // waves 0-3: oc 0-31, waves 4-7: oc 32-63
    float sum = fws[wb*32+ocl] + fws[(wb+1)*32+ocl] + fws[(wb+2)*32+ocl] + fws[(wb+3)*32+ocl];
    partial[(b*8 + t)*64 + tid] = sum;
  }
}

// =============== kfc: reduce partials + fc1 + ht + fc2 -> out[B,2] ======================
__global__ __launch_bounds__(64) void kfc(const float* __restrict__ partial,
    const float* __restrict__ rms, const float* __restrict__ fc1w,
    const float* __restrict__ fc1b, const float* __restrict__ fc2w,
    const float* __restrict__ fc2b, float* __restrict__ out){
  __shared__ float feat[64];
  __shared__ float hbuf[32];
  const int b = blockIdx.x, tid = threadIdx.x;
  float s = 0.f;
  #pragma unroll
  for(int t = 0; t < 8; ++t) s += partial[(b*8 + t)*64 + tid];
  feat[tid] = s * (1.f/256.f);
  __syncthreads();
  if(tid < 32){
    float acc = fc1b[tid];
    const float* wv = &fc1w[tid*65];
    #pragma unroll
    for(int c = 0; c < 64; ++c) acc += wv[c]*feat[c];
    acc += wv[64]*rms[b];
    hbuf[tid] = ht(acc);
  }
  __syncthreads();
  if(tid < 2){
    float acc = fc2b[tid];
    const float* wv = &fc2w[tid*32];
    #pragma unroll
    for(int j = 0; j < 32; ++j) acc += wv[j]*hbuf[j];
    out[b*2 + tid] = acc;
  }
}

extern "C" void kernel_launch(void* const* d_in, const int* in_sizes, int n_in,
                              void* d_out, int out_size, void* d_ws, size_t ws_size,
                              hipStream_t stream){
  (void)in_sizes; (void)n_in; (void)out_size; (void)ws_size;
  const float* x    = (const float*)d_in[0];
  const float* rms  = (const float*)d_in[1];
  const float* w1   = (const float*)d_in[2];
  const float* g1   = (const float*)d_in[3];
  const float* b1   = (const float*)d_in[4];
  const float* m1   = (const float*)d_in[5];
  const float* v1   = (const float*)d_in[6];
  const float* w2   = (const float*)d_in[7];
  const float* g2   = (const float*)d_in[8];
  const float* b2   = (const float*)d_in[9];
  const float* m2   = (const float*)d_in[10];
  const float* v2   = (const float*)d_in[11];
  const float* w3   = (const float*)d_in[12];
  const float* g3   = (const float*)d_in[13];
  const float* b3   = (const float*)d_in[14];
  const float* m3   = (const float*)d_in[15];
  const float* v3   = (const float*)d_in[16];
  const float* fc1w = (const float*)d_in[17];
  const float* fc1b = (const float*)d_in[18];
  const float* fc2w = (const float*)d_in[19];
  const float* fc2b = (const float*)d_in[20];
  float* out  = (float*)d_out;

  // ws layout
  float*          partial = (float*)d_ws;                      // 256*8*64 f32 (512 KB)
  unsigned short* a1  = (unsigned short*)(partial + 131072);   //   512 bf16
  unsigned short* a2  = a1 + 512;                              //  5120 bf16
  unsigned short* a3  = a2 + 5120;                             // 10240 bf16
  float*          bnp = (float*)(a3 + 10240);                  //   224 f32 (16B aligned)

  prep<<<6,    512, 0, stream>>>(w1, w2, w3, g1,b1,m1,v1, g2,b2,m2,v2, g3,b3,m3,v3,
                                 a1, a2, a3, bnp);
  kfused<<<2048, 512, 0, stream>>>(x, a1, a2, a3, bnp, partial);
  kfc<<<256, 64, 0, stream>>>(partial, rms, fc1w, fc1b, fc2w, fc2b, out);
}

// Round 13
// 130.633 us; speedup vs baseline: 1.5162x; 1.0307x over previous
//
#include <hip/hip_runtime.h>
#include <hip/hip_bf16.h>

#define EPS 1e-5f

typedef float f32x4 __attribute__((ext_vector_type(4)));
typedef short s16x8 __attribute__((ext_vector_type(8)));

union FragU { uint4 u; s16x8 s; };

// clamp via single v_med3_f32
__device__ __forceinline__ float ht(float x){ return __builtin_amdgcn_fmed3f(x, -1.f, 1.f); }
__device__ __forceinline__ float sgn(float v){ return (v>0.f)?1.f:((v<0.f)?-1.f:0.f); }
__device__ __forceinline__ unsigned short f2bf(float f){
    unsigned int u = __builtin_bit_cast(unsigned int, f);
    u += 0x7FFFu + ((u>>16)&1u);                 // RNE to bf16
    return (unsigned short)(u>>16);
}
// packed pair f32x2 -> bf16x2 (v_cvt_pk_bf16_f32 on gfx950; RNE either way).
// NOTE: __hip_bfloat162 is not trivially copyable -> extract bits via memcpy (free).
__device__ __forceinline__ unsigned pkbf(float a, float b){
    __hip_bfloat162 h = __float22bfloat162_rn(float2{a, b});
    unsigned u;
    __builtin_memcpy(&u, &h, sizeof(u));
    return u;
}

// DPP cross-lane on the VALU pipe (removes ds_swizzle from the DS pipe).
#define DPP_XOR1 0xB1   // quad_perm(1,0,3,2): swap adjacent lanes
#define DPP_ROR1 0x121  // row (16-lane) rotate by 1
#define DPP_ROR2 0x122
#define DPP_ROR4 0x124
#define DPP_ROR8 0x128
template<int C>
__device__ __forceinline__ float dppf(float x){
  return __builtin_bit_cast(float, __builtin_amdgcn_update_dpp(
      0, __builtin_bit_cast(int, x), C, 0xF, 0xF, true));
}
__device__ __forceinline__ float poolmax(float r){ return fmaxf(r, dppf<DPP_XOR1>(r)); }
__device__ __forceinline__ float rowsum16(float s){   // full sum across the 16-lane row
  s += dppf<DPP_ROR8>(s); s += dppf<DPP_ROR4>(s);
  s += dppf<DPP_ROR2>(s); s += dppf<DPP_ROR1>(s);
  return s;                                           // pairs duplicated -> caller x0.5
}

// =============== prep (6 blocks): A-fragments + BN params ===============
__global__ __launch_bounds__(512) void prep(
    const float* __restrict__ w1, const float* __restrict__ w2, const float* __restrict__ w3,
    const float* g1,const float* b1,const float* m1,const float* v1,
    const float* g2,const float* b2,const float* m2,const float* v2,
    const float* g3,const float* b3,const float* m3,const float* v3,
    unsigned short* __restrict__ a1, unsigned short* __restrict__ a2,
    unsigned short* __restrict__ a3, float* __restrict__ bn){
  const int t = threadIdx.x, bid = blockIdx.x;
  if(bid == 0){
    if(t < 64){                                  // conv1: K=32 (k<17 real)
      int q = t>>4, m = t&15;
      #pragma unroll
      for(int j=0;j<8;++j){ int k = 8*q+j;
        a1[t*8+j] = f2bf((k<17)? w1[m*17+k] : 0.f); }
    }
    if(t<16){ float s = g1[t]*rsqrtf(v1[t]+EPS); bn[t]    = s; bn[16+t]  = b1[t]-m1[t]*s; }
    if(t<32){ float s = g2[t]*rsqrtf(v2[t]+EPS); bn[32+t] = s; bn[64+t]  = b2[t]-m2[t]*s; }
    if(t<64){ float s = g3[t]*rsqrtf(v3[t]+EPS); bn[96+t] = s; bn[160+t] = b3[t]-m3[t]*s; }
  } else if(bid <= 2){                           // conv2: [h2][c5][q4][m16], k-major K=160
    int e = (bid-1)*512 + t;
    if(e < 640){
      int m = e&15, q = (e>>4)&3, hc = e>>6, c = hc%5, h = hc/5;
      int oc = m + 16*h, k = 2*c + (q>>1);
      #pragma unroll
      for(int j=0;j<8;++j){ int ic = 8*(q&1)+j;
        a2[e*8+j] = f2bf((k<9)? sgn(w2[(oc*16+ic)*9+k]) : 0.f); }
    }
  } else {                                       // conv3: [g4][c5][q4][m16], K=160
    int e = (bid-3)*512 + t;
    if(e < 1280){
      int m = e&15, q = (e>>4)&3, gc = e>>6, c = gc%5, g = gc/5;
      int oc = m + 16*g;
      #pragma unroll
      for(int j=0;j<8;++j){ int ic = 8*q+j;
        a3[e*8+j] = f2bf(sgn(w3[(oc*32+ic)*5+c])); }
    }
  }
}

// =============== fused: x -> conv1 -> conv2 -> conv3 -> partial feature sums ===========
// Block owns 32 final pooled positions [Q0,Q0+32), Q0 = 32*(blockIdx&7). Grid = 256*8.
// ~43 KB LDS -> 3 blocks/CU; launch_bounds(512,4): VGPR cap 128, no spill.
// Cross-lane via DPP; conversions via v_cvt_pk_bf16_f32; clamps via v_med3_f32.
__global__ __launch_bounds__(512, 4) void kfused(const float* __restrict__ x,
    const unsigned short* __restrict__ a1, const unsigned short* __restrict__ a2,
    const unsigned short* __restrict__ a3, const float* __restrict__ bn,
    float* __restrict__ partial){
  __shared__ __align__(16) unsigned short xs[2176];      // x[x0 .. x0+2176) bf16
  __shared__ __align__(16) unsigned short s1[552*24];    // [p1 local][16 oc], pad 24
  __shared__ __align__(16) unsigned short s2[132*40];    // [p2 local][32 oc], pad 40
  __shared__ float fws[8*32];
  const int b  = blockIdx.x >> 3;
  const int t  = blockIdx.x & 7;
  const int Q0 = 32*t;
  const int tid = threadIdx.x;
  const int m = tid & 15, q = (tid & 63) >> 4, w = tid >> 6;

  // ---- stage x -> xs ----
  const int x0 = 64*Q0 - 56;
  const float* xrow = &x[b*16384];
  for(int i = tid; i < 544; i += 512){
    int g0 = x0 + 4*i;
    float4 v = make_float4(0.f,0.f,0.f,0.f);
    if(g0 >= 0 && g0 <= 16380) v = *(const float4*)&xrow[g0];
    uint2 pk;
    pk.x = pkbf(v.x, v.y);
    pk.y = pkbf(v.z, v.w);
    *(uint2*)&xs[4*i] = pk;
  }
  FragU af1; af1.u = *(const uint4*)&a1[(q*16+m)*8];
  const float4 sc1 = *(const float4*)&bn[4*q];
  const float4 sh1 = *(const float4*)&bn[16+4*q];
  __syncthreads();

  // ---- stage 1: conv1 on 1072 pre-pool columns (67 tiles) -> s1[536][16] ----
  const unsigned* X32 = (const unsigned*)xs;
  for(int it = 0; it < 9; ++it){
    int tile = it*8 + w;                         // wave-uniform guard
    if(tile < 67){
      int nl = tile*16 + m;
      int d = nl + 4*q;
      FragU bf;
      bf.u.x = X32[d]; bf.u.y = X32[d+1]; bf.u.z = X32[d+2]; bf.u.w = X32[d+3];
      f32x4 acc = {0.f,0.f,0.f,0.f};
      acc = __builtin_amdgcn_mfma_f32_16x16x32_bf16(af1.s, bf.s, acc, 0,0,0);
      float p0 = poolmax(ht(acc[0]*sc1.x + sh1.x));
      float p1 = poolmax(ht(acc[1]*sc1.y + sh1.y));
      float p2 = poolmax(ht(acc[2]*sc1.z + sh1.z));
      float p3 = poolmax(ht(acc[3]*sc1.w + sh1.w));
      if((m&1)==0){
        int ppl = nl >> 1;
        bool ok = (unsigned)(16*Q0 - 12 + ppl) < 4096u;  // reference zero-pad
        uint2 pk;
        pk.x = ok ? pkbf(p0, p1) : 0u;
        pk.y = ok ? pkbf(p2, p3) : 0u;
        *(uint2*)&s1[ppl*24 + 4*q] = pk;
      }
    }
  }
  __syncthreads();

  // ---- stage 2: conv2 on 264 pre-pool columns (17 tiles) -> s2[132][32] ----
  FragU af2[2][5];
  #pragma unroll
  for(int h=0;h<2;++h)
    #pragma unroll
    for(int c=0;c<5;++c)
      af2[h][c].u = *(const uint4*)&a2[(((h*5+c)*4+q)*16+m)*8];
  float4 sc2[2], sh2[2];
  #pragma unroll
  for(int h=0;h<2;++h){
    sc2[h] = *(const float4*)&bn[32 + 16*h + 4*q];
    sh2[h] = *(const float4*)&bn[64 + 16*h + 4*q];
  }
  for(int it = 0; it < 3; ++it){
    int tile = it*8 + w;                         // wave-uniform guard
    if(tile < 17){
      int nl = tile*16 + m;
      f32x4 acc[2] = {{0.f,0.f,0.f,0.f},{0.f,0.f,0.f,0.f}};
      #pragma unroll
      for(int c=0;c<5;++c){
        int row = 2*nl + 2*c + (q>>1);           // row <= 551 < 552
        FragU bf; bf.u = *(const uint4*)&s1[row*24 + 8*(q&1)];
        acc[0] = __builtin_amdgcn_mfma_f32_16x16x32_bf16(af2[0][c].s, bf.s, acc[0],0,0,0);
        acc[1] = __builtin_amdgcn_mfma_f32_16x16x32_bf16(af2[1][c].s, bf.s, acc[1],0,0,0);
      }
      #pragma unroll
      for(int h=0;h<2;++h){
        float p0 = poolmax(ht(acc[h][0]*sc2[h].x + sh2[h].x));
        float p1 = poolmax(ht(acc[h][1]*sc2[h].y + sh2[h].y));
        float p2 = poolmax(ht(acc[h][2]*sc2[h].z + sh2[h].z));
        float p3 = poolmax(ht(acc[h][3]*sc2[h].w + sh2[h].w));
        if((m&1)==0 && nl < 264){
          int ppl = nl >> 1;
          bool ok = (unsigned)(4*Q0 - 2 + ppl) < 1024u;  // reference zero-pad
          uint2 pk;
          pk.x = ok ? pkbf(p0, p1) : 0u;
          pk.y = ok ? pkbf(p2, p3) : 0u;
          *(uint2*)&s2[ppl*40 + 16*h + 4*q] = pk;
        }
      }
    }
  }
  __syncthreads();

  // ---- stage 3: conv3 on 64 pre-pool columns; wave = (tile w&3, oc-half w>>2) ----
  const int gw = w >> 2, tw = w & 3;
  FragU af3[2][5];
  #pragma unroll
  for(int gl=0;gl<2;++gl)
    #pragma unroll
    for(int c=0;c<5;++c)
      af3[gl][c].u = *(const uint4*)&a3[((((2*gw+gl)*5+c)*4+q)*16+m)*8];
  float4 sc3[2], sh3[2];
  #pragma unroll
  for(int gl=0;gl<2;++gl){
    sc3[gl] = *(const float4*)&bn[96  + 16*(2*gw+gl) + 4*q];
    sh3[gl] = *(const float4*)&bn[160 + 16*(2*gw+gl) + 4*q];
  }
  {
    int nl = tw*16 + m;
    f32x4 acc[2] = {{0.f,0.f,0.f,0.f},{0.f,0.f,0.f,0.f}};
    #pragma unroll
    for(int c=0;c<5;++c){
      int row = 2*nl + c;                        // row <= 130 < 132
      FragU bf; bf.u = *(const uint4*)&s2[row*40 + 8*q];
      acc[0] = __builtin_amdgcn_mfma_f32_16x16x32_bf16(af3[0][c].s, bf.s, acc[0],0,0,0);
      acc[1] = __builtin_amdgcn_mfma_f32_16x16x32_bf16(af3[1][c].s, bf.s, acc[1],0,0,0);
    }
    #pragma unroll
    for(int gl=0;gl<2;++gl){
      float p0 = poolmax(ht(acc[gl][0]*sc3[gl].x + sh3[gl].x));
      float p1 = poolmax(ht(acc[gl][1]*sc3[gl].y + sh3[gl].y));
      float p2 = poolmax(ht(acc[gl][2]*sc3[gl].z + sh3[gl].z));
      float p3 = poolmax(ht(acc[gl][3]*sc3[gl].w + sh3[gl].w));
      // 16-lane rotate-sum counts each pooled value TWICE (pairs duplicated) -> x0.5
      float s0 = rowsum16(p0)*0.5f, s1v = rowsum16(p1)*0.5f;
      float s2v = rowsum16(p2)*0.5f, s3 = rowsum16(p3)*0.5f;
      if(m == 0)
        *(float4*)&fws[w*32 + 16*gl + 4*q] = make_float4(s0,s1v,s2v,s3);
    }
  }
  __syncthreads();
  if(tid < 64){
    int ocl = tid & 31;
    int wb  = (tid >> 5) * 4;                    // waves 0-3: oc 0-31, waves 4-7: oc 32-63
    float sum = fws[wb*32+ocl] + fws[(wb+1)*32+ocl] + fws[(wb+2)*32+ocl] + fws[(wb+3)*32+ocl];
    partial[(b*8 + t)*64 + tid] = sum;
  }
}

// =============== kfc: reduce partials + fc1 + ht + fc2 -> out[B,2] ======================
__global__ __launch_bounds__(64) void kfc(const float* __restrict__ partial,
    const float* __restrict__ rms, const float* __restrict__ fc1w,
    const float* __restrict__ fc1b, const float* __restrict__ fc2w,
    const float* __restrict__ fc2b, float* __restrict__ out){
  __shared__ float feat[64];
  __shared__ float hbuf[32];
  const int b = blockIdx.x, tid = threadIdx.x;
  float s = 0.f;
  #pragma unroll
  for(int t = 0; t < 8; ++t) s += partial[(b*8 + t)*64 + tid];
  feat[tid] = s * (1.f/256.f);
  __syncthreads();
  if(tid < 32){
    float acc = fc1b[tid];
    const float* wv = &fc1w[tid*65];
    #pragma unroll
    for(int c = 0; c < 64; ++c) acc += wv[c]*feat[c];
    acc += wv[64]*rms[b];
    hbuf[tid] = ht(acc);
  }
  __syncthreads();
  if(tid < 2){
    float acc = fc2b[tid];
    const float* wv = &fc2w[tid*32];
    #pragma unroll
    for(int j = 0; j < 32; ++j) acc += wv[j]*hbuf[j];
    out[b*2 + tid] = acc;
  }
}

extern "C" void kernel_launch(void* const* d_in, const int* in_sizes, int n_in,
                              void* d_out, int out_size, void* d_ws, size_t ws_size,
                              hipStream_t stream){
  (void)in_sizes; (void)n_in; (void)out_size; (void)ws_size;
  const float* x    = (const float*)d_in[0];
  const float* rms  = (const float*)d_in[1];
  const float* w1   = (const float*)d_in[2];
  const float* g1   = (const float*)d_in[3];
  const float* b1   = (const float*)d_in[4];
  const float* m1   = (const float*)d_in[5];
  const float* v1   = (const float*)d_in[6];
  const float* w2   = (const float*)d_in[7];
  const float* g2   = (const float*)d_in[8];
  const float* b2   = (const float*)d_in[9];
  const float* m2   = (const float*)d_in[10];
  const float* v2   = (const float*)d_in[11];
  const float* w3   = (const float*)d_in[12];
  const float* g3   = (const float*)d_in[13];
  const float* b3   = (const float*)d_in[14];
  const float* m3   = (const float*)d_in[15];
  const float* v3   = (const float*)d_in[16];
  const float* fc1w = (const float*)d_in[17];
  const float* fc1b = (const float*)d_in[18];
  const float* fc2w = (const float*)d_in[19];
  const float* fc2b = (const float*)d_in[20];
  float* out  = (float*)d_out;

  // ws layout
  float*          partial = (float*)d_ws;                      // 256*8*64 f32 (512 KB)
  unsigned short* a1  = (unsigned short*)(partial + 131072);   //   512 bf16
  unsigned short* a2  = a1 + 512;                              //  5120 bf16
  unsigned short* a3  = a2 + 5120;                             // 10240 bf16
  float*          bnp = (float*)(a3 + 10240);                  //   224 f32 (16B aligned)

  prep<<<6,    512, 0, stream>>>(w1, w2, w3, g1,b1,m1,v1, g2,b2,m2,v2, g3,b3,m3,v3,
                                 a1, a2, a3, bnp);
  kfused<<<2048, 512, 0, stream>>>(x, a1, a2, a3, bnp, partial);
  kfc<<<256, 64, 0, stream>>>(partial, rms, fc1w, fc1b, fc2w, fc2b, out);
}